// Round 1
// 511.605 us; speedup vs baseline: 1.0303x; 1.0303x over previous
//
#include <hip/hip_runtime.h>
#include <hip/hip_bf16.h>
#include <cstdint>

typedef short short8 __attribute__((ext_vector_type(8)));
typedef float f32x4 __attribute__((ext_vector_type(4)));
typedef int   int4v __attribute__((ext_vector_type(4)));

using bf16 = __hip_bfloat16;

#define MFMA16(a, b, c) __builtin_amdgcn_mfma_f32_16x16x32_bf16((a), (b), (c), 0, 0, 0)
#define MFMAI8(a, b, c) __builtin_amdgcn_mfma_i32_16x16x64_i8((a), (b), (c), 0, 0, 0)

__device__ __forceinline__ short8 ldb8(const bf16* p) {
    return *reinterpret_cast<const short8*>(p);
}
__device__ __forceinline__ unsigned pk4(int a, int b, int c, int d) {
    return (a & 255) | ((b & 255) << 8) | ((c & 255) << 16) | ((d & 255) << 24);
}

// -------------------------------------------------------------------------
__global__ __launch_bounds__(256) void k_cast(const float* __restrict__ src,
                                              bf16* __restrict__ dst, int n)
{
    for (int i = blockIdx.x * 256 + threadIdx.x; i < n; i += gridDim.x * 256)
        dst[i] = __float2bfloat16(src[i]);
}

// -------------------------------------------------------------------------
// Kernel 1: QKV projection f32, 64x128 tile, 4x8/thread, BK=16.
// Compute identical to previous pass; epilogue now packs int8 operands.
// -------------------------------------------------------------------------
__global__ __launch_bounds__(256, 3) void k_qkv_f32(
    const float* __restrict__ X, const float* __restrict__ W, const float* __restrict__ bq,
    const float* __restrict__ qvm, const float* __restrict__ kvm, const float* __restrict__ vvm,
    const int* __restrict__ qac, const int* __restrict__ kac, const int* __restrict__ vac,
    int8_t* __restrict__ Q2, int8_t* __restrict__ K2c, int8_t* __restrict__ VsT, int8_t* __restrict__ VaT)
{
    __shared__ float As[16][64];
    __shared__ float Bs[16][128];
    const int tid = threadIdx.x;
    const int r0 = blockIdx.y * 64;            // rows (b*N+n)
    const int c0 = blockIdx.x * 128;           // cols (0..1535)
    const int tm = (tid & 15) * 4;             // 4 rows
    const int tn = (tid >> 4) * 8;             // 8 cols
    const int arow = tid >> 2, ak = (tid & 3) * 4;
    const int brow = tid >> 1, bk = (tid & 1) * 8;

    float acc[4][8] = {};
    for (int kk = 0; kk < 512; kk += 16) {
        const float4 a4 = *reinterpret_cast<const float4*>(X + (size_t)(r0 + arow) * 512 + kk + ak);
        const float4 w0 = *reinterpret_cast<const float4*>(W + (size_t)(c0 + brow) * 512 + kk + bk);
        const float4 w1 = *reinterpret_cast<const float4*>(W + (size_t)(c0 + brow) * 512 + kk + bk + 4);
        __syncthreads();
        As[ak + 0][arow] = a4.x; As[ak + 1][arow] = a4.y; As[ak + 2][arow] = a4.z; As[ak + 3][arow] = a4.w;
        Bs[bk + 0][brow] = w0.x; Bs[bk + 1][brow] = w0.y; Bs[bk + 2][brow] = w0.z; Bs[bk + 3][brow] = w0.w;
        Bs[bk + 4][brow] = w1.x; Bs[bk + 5][brow] = w1.y; Bs[bk + 6][brow] = w1.z; Bs[bk + 7][brow] = w1.w;
        __syncthreads();
        #pragma unroll
        for (int k = 0; k < 16; ++k) {
            const float4 av = *reinterpret_cast<const float4*>(&As[k][tm]);
            const float4 bv0 = *reinterpret_cast<const float4*>(&Bs[k][tn]);
            const float4 bv1 = *reinterpret_cast<const float4*>(&Bs[k][tn + 4]);
            const float ar[4] = {av.x, av.y, av.z, av.w};
            const float br[8] = {bv0.x, bv0.y, bv0.z, bv0.w, bv1.x, bv1.y, bv1.z, bv1.w};
            #pragma unroll
            for (int i = 0; i < 4; ++i)
                #pragma unroll
                for (int j = 0; j < 8; ++j)
                    acc[i][j] += ar[i] * br[j];
        }
    }

    const int sel = c0 >> 9;                   // block-uniform (128-col tiles are 512-aligned groups)
    const int h   = ((c0 + tn) & 511) >> 6;    // thread-uniform (8-col group within one head)
    const int d0  = (c0 + tn) & 63;
    const float4 bb0 = *reinterpret_cast<const float4*>(bq + c0 + tn);
    const float4 bb1 = *reinterpret_cast<const float4*>(bq + c0 + tn + 4);
    const float bcol[8] = {bb0.x, bb0.y, bb0.z, bb0.w, bb1.x, bb1.y, bb1.z, bb1.w};

    // load vmem/acc for all 4 rows (8 cols contiguous at d0)
    const float* VM = (sel == 0) ? qvm : (sel == 1) ? kvm : vvm;
    const int*   AC = (sel == 0) ? qac : (sel == 1) ? kac : vac;
    float vmv[4][8]; int acv[4][8]; int bhn[4];
    #pragma unroll
    for (int i = 0; i < 4; ++i) {
        const int r = r0 + tm + i;
        const int b = r >> 10, n = r & 1023;
        const int bh = b * 8 + h;
        bhn[i] = bh * 1024 + n;
        const size_t i4 = (size_t)bhn[i] * 64 + d0;
        const float4 v0 = *reinterpret_cast<const float4*>(VM + i4);
        const float4 v1 = *reinterpret_cast<const float4*>(VM + i4 + 4);
        const int4  c0i = *reinterpret_cast<const int4*>(AC + i4);
        const int4  c1i = *reinterpret_cast<const int4*>(AC + i4 + 4);
        vmv[i][0]=v0.x; vmv[i][1]=v0.y; vmv[i][2]=v0.z; vmv[i][3]=v0.w;
        vmv[i][4]=v1.x; vmv[i][5]=v1.y; vmv[i][6]=v1.z; vmv[i][7]=v1.w;
        acv[i][0]=c0i.x; acv[i][1]=c0i.y; acv[i][2]=c0i.z; acv[i][3]=c0i.w;
        acv[i][4]=c1i.x; acv[i][5]=c1i.y; acv[i][6]=c1i.z; acv[i][7]=c1i.w;
    }

    int spm[4][8];
    #pragma unroll
    for (int i = 0; i < 4; ++i)
        #pragma unroll
        for (int j = 0; j < 8; ++j) {
            const float v_ = vmv[i][j] + (acc[i][j] + bcol[j]);
            // acc0 in [0,7] => neg gate's acc0 > -8 always true
            int sp = ((v_ >= 1.0f) && (acv[i][j] < 7)) ? 1 : 0;
            if (v_ < 0.0f) sp -= 1;
            spm[i][j] = sp;
        }

    if (sel == 2) {   // VsT/VaT transposed int8: pack 4 consecutive n per column
        #pragma unroll
        for (int j = 0; j < 8; ++j) {
            const int nb = (r0 & 1023) + tm;
            const unsigned us = pk4(spm[0][j], spm[1][j], spm[2][j], spm[3][j]);
            const unsigned ua = pk4(acv[0][j], acv[1][j], acv[2][j], acv[3][j]);
            const size_t vi = ((size_t)((bhn[0] >> 10) * 64 + d0 + j)) * 1024 + nb;
            *reinterpret_cast<unsigned*>(VsT + vi) = us;
            *reinterpret_cast<unsigned*>(VaT + vi) = ua;
        }
    } else {
        #pragma unroll
        for (int i = 0; i < 4; ++i) {
            int v0[8], v1[8];
            #pragma unroll
            for (int j = 0; j < 8; ++j) {
                if (sel == 0) { v0[j] = acv[i][j] + spm[i][j]; v1[j] = spm[i][j]; }
                else          { v0[j] = spm[i][j];             v1[j] = acv[i][j]; }
            }
            uint2 a, b;
            a.x = pk4(v0[0], v0[1], v0[2], v0[3]); a.y = pk4(v0[4], v0[5], v0[6], v0[7]);
            b.x = pk4(v1[0], v1[1], v1[2], v1[3]); b.y = pk4(v1[4], v1[5], v1[6], v1[7]);
            int8_t* base = ((sel == 0) ? Q2 : K2c) + (size_t)bhn[i] * 128 + d0;
            *reinterpret_cast<uint2*>(base)      = a;
            *reinterpret_cast<uint2*>(base + 64) = b;
        }
    }
}

// -------------------------------------------------------------------------
// Kernel 2 (fused, int8/int16 edition, 32 KiB LDS, 4 blocks/CU):
//   P1: i8 MFMA scores -> S int16 (exact |S|<=960)
//   P2: scores -> 8x short8 registers; softmax max/sum from regs (exact max;
//       sum reordered at ulp level only); e recomputed in P-pass (bit-same expr)
//   P3: attn-IF + P1/P2 int8 pack overlaying S (row-XOR swizzled);
//       avm/aac streamed through a 3-slot register pipeline
//   P4: PV via i8 MFMA (exact i32), after-IF, O2 bf16
// -------------------------------------------------------------------------
__global__ __launch_bounds__(256, 4) void k_attn(
    const int8_t* __restrict__ Q2, const int8_t* __restrict__ K2c,
    const float* __restrict__ avm, const int* __restrict__ aac,
    const int8_t* __restrict__ VsT, const int8_t* __restrict__ VaT,
    bf16* __restrict__ O2)
{
    __shared__ alignas(16) char Sc[32768];
    short* const Ss = (short*)Sc;
    const int w = threadIdx.x >> 6, lane = threadIdx.x & 63;
    const int lo = lane & 15, hi = lane >> 4;
    const int h = blockIdx.y, bb = blockIdx.z;
    const int bh = bb * 8 + h;
    const int n0 = blockIdx.x * 16;

    // ---- Phase 1: scores (i8 MFMA, K=64 x2) -> S int16 ----
    {
        const int8_t* qb = Q2 + ((size_t)(bh * 1024 + n0 + lo)) * 128 + hi * 16;
        const int4v a0 = *reinterpret_cast<const int4v*>(qb);
        const int4v a1 = *reinterpret_cast<const int4v*>(qb + 64);
        const int8_t* kbp = K2c + ((size_t)(bh * 1024 + w * 256 + lo)) * 128 + hi * 16;
        int4v b0 = *reinterpret_cast<const int4v*>(kbp);
        int4v b1 = *reinterpret_cast<const int4v*>(kbp + 64);
        for (int t = 0; t < 16; ++t) {
            const int4v c0f = b0, c1f = b1;
            if (t < 15) {
                kbp += 16 * 128;
                b0 = *reinterpret_cast<const int4v*>(kbp);
                b1 = *reinterpret_cast<const int4v*>(kbp + 64);
            }
            int4v acc = {0, 0, 0, 0};
            acc = MFMAI8(a0, c0f, acc);
            acc = MFMAI8(a1, c1f, acc);
            const int cc = w * 256 + t * 16 + lo;
            short* sb = Ss + ((cc >> 9) << 13) + (cc & 511);
            #pragma unroll
            for (int r = 0; r < 4; ++r)
                sb[(hi * 4 + r) << 9] = (short)acc[r];
        }
    }

    const int row = threadIdx.x >> 4, q = threadIdx.x & 15;
    const size_t gRow = ((size_t)bh * 1024 + (n0 + row)) * 1024;

#define LOADJ(j, VM0, VM1, AC0, AC1) {                                          \
        const int cb_ = (q + 16 * (j)) * 8;                                     \
        VM0 = *reinterpret_cast<const float4*>(avm + gRow + cb_);               \
        VM1 = *reinterpret_cast<const float4*>(avm + gRow + cb_ + 4);           \
        AC0 = *reinterpret_cast<const int4*>(aac + gRow + cb_);                 \
        AC1 = *reinterpret_cast<const int4*>(aac + gRow + cb_ + 4); }

    float4 vmA0, vmA1, vmB0, vmB1, vmC0, vmC1;
    int4   acA0, acA1, acB0, acB1, acC0, acC1;
    LOADJ(0, vmA0, vmA1, acA0, acA1);
    LOADJ(1, vmB0, vmB1, acB0, acB1);

    __syncthreads();   // S writes visible

    // ---- Phase 2a: scores -> registers (this thread's 64 cols) ----
    short8 sc[8];
    #pragma unroll
    for (int j = 0; j < 8; ++j) {
        const int kb = q + 16 * j;
        sc[j] = *reinterpret_cast<const short8*>(Sc + ((kb >> 6) << 14) + (row << 10) + ((kb & 63) << 4));
    }
    __syncthreads();   // all score reads done; S space free for P overlay

    LOADJ(2, vmC0, vmC1, acC0, acC1);

    // ---- Phase 2b: max (exact, any order) / sum (ulp-level reorder) ----
    int mxi = sc[0][0];
    #pragma unroll
    for (int j = 0; j < 8; ++j)
        #pragma unroll
        for (int i = 0; i < 8; ++i)
            mxi = max(mxi, (int)sc[j][i]);
    float mx = 0.125f * (float)mxi;
    mx = fmaxf(mx, __shfl_xor(mx, 1));
    mx = fmaxf(mx, __shfl_xor(mx, 2));
    mx = fmaxf(mx, __shfl_xor(mx, 4));
    mx = fmaxf(mx, __shfl_xor(mx, 8));

    float sum = 0.f;
    #pragma unroll
    for (int j = 0; j < 8; ++j)
        #pragma unroll
        for (int i = 0; i < 8; ++i)
            sum += expf(0.125f * (float)sc[j][i] - mx);
    sum += __shfl_xor(sum, 1);
    sum += __shfl_xor(sum, 2);
    sum += __shfl_xor(sum, 4);
    sum += __shfl_xor(sum, 8);

    // ---- Phase 3: attn-IF + int8 P pack (overlay S; row-XOR swizzle) ----
#define PSTEP(j, VM0, VM1, AC0, AC1) {                                          \
        const float vmr_[8] = {VM0.x, VM0.y, VM0.z, VM0.w,                      \
                               VM1.x, VM1.y, VM1.z, VM1.w};                     \
        const int aar_[8] = {AC0.x, AC0.y, AC0.z, AC0.w,                        \
                             AC1.x, AC1.y, AC1.z, AC1.w};                       \
        unsigned p1u[8], p2u[8];                                                \
        _Pragma("unroll")                                                       \
        for (int i = 0; i < 8; ++i) {                                           \
            const float e_ = expf(0.125f * (float)sc[j][i] - mx);               \
            const float p7 = (e_ / sum) * 7.0f;                                 \
            const float v_ = (vmr_[i] + 0.2f) + p7;  /* v_ > 0 always */        \
            const int a0i = aar_[i];                 /* in [0,7] */             \
            const int sp = ((v_ >= 1.0f) && (a0i < 7)) ? 1 : 0;                 \
            p1u[i] = (unsigned)(a0i + sp);                                      \
            p2u[i] = (unsigned)sp;                                              \
        }                                                                       \
        uint2 w1, w2;                                                           \
        w1.x = p1u[0] | (p1u[1] << 8) | (p1u[2] << 16) | (p1u[3] << 24);        \
        w1.y = p1u[4] | (p1u[5] << 8) | (p1u[6] << 16) | (p1u[7] << 24);        \
        w2.x = p2u[0] | (p2u[1] << 8) | (p2u[2] << 16) | (p2u[3] << 24);        \
        w2.y = p2u[4] | (p2u[5] << 8) | (p2u[6] << 16) | (p2u[7] << 24);        \
        const int kb = q + 16 * (j);                                            \
        char* pb = Sc + (row << 10) + (((kb << 3) ^ ((row & 7) << 4)));         \
        *reinterpret_cast<uint2*>(pb)         = w1;                             \
        *reinterpret_cast<uint2*>(pb + 16384) = w2; }

    PSTEP(0, vmA0, vmA1, acA0, acA1);
    LOADJ(3, vmA0, vmA1, acA0, acA1);
    PSTEP(1, vmB0, vmB1, acB0, acB1);
    LOADJ(4, vmB0, vmB1, acB0, acB1);
    PSTEP(2, vmC0, vmC1, acC0, acC1);
    LOADJ(5, vmC0, vmC1, acC0, acC1);
    PSTEP(3, vmA0, vmA1, acA0, acA1);
    LOADJ(6, vmA0, vmA1, acA0, acA1);
    PSTEP(4, vmB0, vmB1, acB0, acB1);
    LOADJ(7, vmB0, vmB1, acB0, acB1);
    PSTEP(5, vmC0, vmC1, acC0, acC1);
    PSTEP(6, vmA0, vmA1, acA0, acA1);
    PSTEP(7, vmB0, vmB1, acB0, acB1);

    __syncthreads();   // P fully written

    // ---- Phase 4: PV (i8 MFMA, exact i32), after-attn IF, write O2 ----
    {
        const int d0 = w * 16;
        const int8_t* vs = VsT + ((size_t)(bh * 64 + d0 + lo)) * 1024 + hi * 16;
        const int8_t* va = VaT + ((size_t)(bh * 64 + d0 + lo)) * 1024 + hi * 16;
        int4v nvs = *reinterpret_cast<const int4v*>(vs);
        int4v nva = *reinterpret_cast<const int4v*>(va);
        int4v acc = {0, 0, 0, 0};
        for (int tt = 0; tt < 16; ++tt) {
            const int4v cvs = nvs, cva = nva;
            if (tt < 15) {
                nvs = *reinterpret_cast<const int4v*>(vs + (tt + 1) * 64);
                nva = *reinterpret_cast<const int4v*>(va + (tt + 1) * 64);
            }
            const int off = (tt * 64 + hi * 16) ^ ((lo & 7) << 4);
            const char* pb = Sc + (lo << 10) + off;
            const int4v a1 = *reinterpret_cast<const int4v*>(pb);
            const int4v a2 = *reinterpret_cast<const int4v*>(pb + 16384);
            acc = MFMAI8(a1, cvs, acc);
            acc = MFMAI8(a2, cva, acc);
        }
        #pragma unroll
        for (int r = 0; r < 4; ++r) {
            const int n = n0 + hi * 4 + r;
            const float o = (float)acc[r];          // exact integer
            const float o2 = (o >= 0.5f ? 1.f : 0.f) - (o < -0.5f ? 1.f : 0.f);
            O2[((size_t)(bb * 1024 + n)) * 512 + h * 64 + d0 + lo] = __float2bfloat16(o2);
        }
    }
#undef LOADJ
#undef PSTEP
}

// -------------------------------------------------------------------------
// Kernel 3: Y = O2 @ Wp^T + b_proj, f32 out (unchanged).
// -------------------------------------------------------------------------
__global__ __launch_bounds__(256) void k_proj(
    const bf16* __restrict__ O2, const bf16* __restrict__ W, const float* __restrict__ bias,
    float* __restrict__ Y)
{
    const int w = threadIdx.x >> 6, lane = threadIdx.x & 63;
    const int lo = lane & 15, hi = lane >> 4;
    const int r0 = blockIdx.y * 16;
    const int c0 = blockIdx.x * 256 + w * 64;

    f32x4 acc[4] = {{0.f,0.f,0.f,0.f},{0.f,0.f,0.f,0.f},{0.f,0.f,0.f,0.f},{0.f,0.f,0.f,0.f}};
    const bf16* op = O2 + (size_t)(r0 + lo) * 512 + hi * 8;
    #pragma unroll 4
    for (int kb = 0; kb < 16; ++kb) {
        short8 a = ldb8(op + kb * 32);
        #pragma unroll
        for (int t = 0; t < 4; ++t) {
            short8 b = ldb8(W + (size_t)(c0 + t * 16 + lo) * 512 + kb * 32 + hi * 8);
            acc[t] = MFMA16(a, b, acc[t]);
        }
    }
    #pragma unroll
    for (int t = 0; t < 4; ++t) {
        const int col = c0 + t * 16 + lo;
        const float bcol = bias[col];
        #pragma unroll
        for (int r = 0; r < 4; ++r) {
            const int rr = r0 + hi * 4 + r;
            Y[(size_t)rr * 512 + col] = acc[t][r] + bcol;
        }
    }
}

// -------------------------------------------------------------------------
extern "C" void kernel_launch(void* const* d_in, const int* in_sizes, int n_in,
                              void* d_out, int out_size, void* d_ws, size_t ws_size,
                              hipStream_t stream)
{
    const float* x     = (const float*)d_in[0];
    const float* wqkv  = (const float*)d_in[1];
    const float* bqkv  = (const float*)d_in[2];
    const float* wproj = (const float*)d_in[3];
    const float* bproj = (const float*)d_in[4];
    const float* qvm   = (const float*)d_in[5];
    const float* kvm   = (const float*)d_in[6];
    const float* vvm   = (const float*)d_in[7];
    const float* avm   = (const float*)d_in[8];
    const int*   qac   = (const int*)d_in[9];
    const int*   kac   = (const int*)d_in[10];
    const int*   vac   = (const int*)d_in[11];
    const int*   aac   = (const int*)d_in[12];

    char* p = (char*)d_ws;
    int8_t* Q2  = (int8_t*)p; p += (size_t)32 * 1024 * 128;   // 4 MB  [bh][n][128]
    int8_t* K2c = (int8_t*)p; p += (size_t)32 * 1024 * 128;   // 4 MB  [bh][m][128]
    int8_t* VsT = (int8_t*)p; p += (size_t)32 * 64 * 1024;    // 2 MB  [bh][d][m]
    int8_t* VaT = (int8_t*)p; p += (size_t)32 * 64 * 1024;    // 2 MB
    bf16*   O2  = (bf16*)p;   p += (size_t)4096 * 512 * 2;    // 4 MB  [B*N][C]
    bf16*   Wp  = (bf16*)p;   p += (size_t)512 * 512 * 2;     // 0.5MB w_proj bf16

    k_cast<<<dim3(256), 256, 0, stream>>>(wproj, Wp, 512 * 512);
    k_qkv_f32<<<dim3(12, 64), 256, 0, stream>>>(x, wqkv, bqkv, qvm, kvm, vvm,
                                                qac, kac, vac, Q2, K2c, VsT, VaT);
    k_attn<<<dim3(64, 8, 4), 256, 0, stream>>>(Q2, K2c, avm, aac, VsT, VaT, O2);
    k_proj<<<dim3(2, 256), 256, 0, stream>>>(O2, Wp, bproj, (float*)d_out);
}

// Round 2
// 459.656 us; speedup vs baseline: 1.1467x; 1.1130x over previous
//
#include <hip/hip_runtime.h>
#include <hip/hip_bf16.h>
#include <cstdint>

typedef short short8 __attribute__((ext_vector_type(8)));
typedef float f32x4 __attribute__((ext_vector_type(4)));
typedef int   int4v __attribute__((ext_vector_type(4)));
typedef _Float16 fp16x8 __attribute__((ext_vector_type(8)));

using bf16 = __hip_bfloat16;

#define MFMA16(a, b, c) __builtin_amdgcn_mfma_f32_16x16x32_bf16((a), (b), (c), 0, 0, 0)
#define MFMAI8(a, b, c) __builtin_amdgcn_mfma_i32_16x16x64_i8((a), (b), (c), 0, 0, 0)
#define MFMAF16(a, b, c) __builtin_amdgcn_mfma_f32_16x16x32_f16((a), (b), (c), 0, 0, 0)

__device__ __forceinline__ short8 ldb8(const bf16* p) {
    return *reinterpret_cast<const short8*>(p);
}

// -------------------------------------------------------------------------
// Prep: split X and W into f16 hi/lo pairs (Dekker, scaled by 512 to stay
// clear of f16 denormals; all scales are powers of 2 => exact), cast Wp.
//   Xs = X*512 = Xh + Xl*2^-11 + O(2^-23)
// -------------------------------------------------------------------------
__global__ __launch_bounds__(256) void k_prep(
    const float* __restrict__ X, const float* __restrict__ W, const float* __restrict__ Wp,
    _Float16* __restrict__ Xh, _Float16* __restrict__ Xl,
    _Float16* __restrict__ Wh, _Float16* __restrict__ Wl, bf16* __restrict__ Wpb)
{
    const int NX = 4096 * 512, NW = 1536 * 512, NP = 512 * 512;
    for (int i = blockIdx.x * 256 + threadIdx.x; i < NX + NW + NP; i += gridDim.x * 256) {
        if (i < NX) {
            const float v = X[i] * 512.0f;
            const _Float16 h = (_Float16)v;
            Xh[i] = h;
            Xl[i] = (_Float16)((v - (float)h) * 2048.0f);
        } else if (i < NX + NW) {
            const int j = i - NX;
            const float v = W[j] * 512.0f;
            const _Float16 h = (_Float16)v;
            Wh[j] = h;
            Wl[j] = (_Float16)((v - (float)h) * 2048.0f);
        } else {
            const int j = i - NX - NW;
            Wpb[j] = __float2bfloat16(Wp[j]);
        }
    }
}

// -------------------------------------------------------------------------
// Kernel 1: QKV projection via f16x2-split MFMA (f32-class accuracy).
//   acc = (hh + md*2^-11) * 2^-18
// Block: 64 rows x 128 cols, 4 waves of 32x64, no LDS (direct-global frags).
// Epilogue: IF spike logic + int8 packing for k_attn (unchanged layouts).
// -------------------------------------------------------------------------
__global__ __launch_bounds__(256, 3) void k_qkv_f16(
    const _Float16* __restrict__ Xh, const _Float16* __restrict__ Xl,
    const _Float16* __restrict__ Wh, const _Float16* __restrict__ Wl,
    const float* __restrict__ bq,
    const float* __restrict__ qvm, const float* __restrict__ kvm, const float* __restrict__ vvm,
    const int* __restrict__ qac, const int* __restrict__ kac, const int* __restrict__ vac,
    int8_t* __restrict__ Q2, int8_t* __restrict__ K2c,
    int8_t* __restrict__ VsT, int8_t* __restrict__ VaT)
{
    const int tid = threadIdx.x;
    const int w = tid >> 6, lane = tid & 63, lo = lane & 15, hi = lane >> 4;
    const int wr = w >> 1, wc = w & 1;
    const int r0 = blockIdx.y * 64 + wr * 32;      // 32 rows for this wave
    const int c0 = blockIdx.x * 128 + wc * 64;     // 64 cols for this wave

    f32x4 hh[2][4] = {};
    f32x4 md[2][4] = {};

    const _Float16* xhp = Xh + (size_t)(r0 + lo) * 512 + hi * 8;
    const _Float16* xlp = Xl + (size_t)(r0 + lo) * 512 + hi * 8;
    const _Float16* whp = Wh + (size_t)(c0 + lo) * 512 + hi * 8;
    const _Float16* wlp = Wl + (size_t)(c0 + lo) * 512 + hi * 8;

    for (int kc = 0; kc < 16; ++kc) {
        const int ko = kc * 32;
        const fp16x8 Ah0 = *reinterpret_cast<const fp16x8*>(xhp + ko);
        const fp16x8 Ah1 = *reinterpret_cast<const fp16x8*>(xhp + ko + 16 * 512);
        const fp16x8 Al0 = *reinterpret_cast<const fp16x8*>(xlp + ko);
        const fp16x8 Al1 = *reinterpret_cast<const fp16x8*>(xlp + ko + 16 * 512);
        fp16x8 Bh[4], Bl[4];
        #pragma unroll
        for (int j = 0; j < 4; ++j) {
            Bh[j] = *reinterpret_cast<const fp16x8*>(whp + ko + j * 16 * 512);
            Bl[j] = *reinterpret_cast<const fp16x8*>(wlp + ko + j * 16 * 512);
        }
        #pragma unroll
        for (int j = 0; j < 4; ++j) {
            hh[0][j] = MFMAF16(Ah0, Bh[j], hh[0][j]);
            hh[1][j] = MFMAF16(Ah1, Bh[j], hh[1][j]);
            md[0][j] = MFMAF16(Ah0, Bl[j], md[0][j]);
            md[0][j] = MFMAF16(Al0, Bh[j], md[0][j]);
            md[1][j] = MFMAF16(Ah1, Bl[j], md[1][j]);
            md[1][j] = MFMAF16(Al1, Bh[j], md[1][j]);
        }
    }

    // ---- epilogue: IF spikes + int8 pack ----
    const int sel = (unsigned)c0 >> 9;             // block-group uniform (tiles never straddle 512)
    const float* VM = (sel == 0) ? qvm : (sel == 1) ? kvm : vvm;
    const int*   AC = (sel == 0) ? qac : (sel == 1) ? kac : vac;

    #pragma unroll
    for (int i = 0; i < 2; ++i) {
        const int rowb = r0 + i * 16 + hi * 4;     // 4 consecutive rows rowb..rowb+3
        const int b = rowb >> 10, nb = rowb & 1023;
        #pragma unroll
        for (int j = 0; j < 4; ++j) {
            const int c = c0 + j * 16 + lo;
            const int ch = c & 511;
            const int hh_ = ch >> 6, d = ch & 63;
            const int bh = b * 8 + hh_;
            const float bcol = bq[c];
            int sp[4], a4[4];
            #pragma unroll
            for (int r = 0; r < 4; ++r) {
                const size_t gi = (size_t)(bh * 1024 + nb + r) * 64 + d;
                const float vm = VM[gi];
                const int a0 = AC[gi];
                const float val = fmaf(md[i][j][r], 0x1p-11f, hh[i][j][r]) * 0x1p-18f;
                const float v_ = vm + (val + bcol);
                int s = ((v_ >= 1.0f) && (a0 < 7)) ? 1 : 0;
                if (v_ < 0.0f) s -= 1;
                sp[r] = s; a4[r] = a0;
            }
            if (sel == 2) {
                uchar4 us, ua;
                us.x = (uint8_t)sp[0]; us.y = (uint8_t)sp[1]; us.z = (uint8_t)sp[2]; us.w = (uint8_t)sp[3];
                ua.x = (uint8_t)a4[0]; ua.y = (uint8_t)a4[1]; ua.z = (uint8_t)a4[2]; ua.w = (uint8_t)a4[3];
                const size_t vi = (size_t)(bh * 64 + d) * 1024 + nb;   // nb % 4 == 0
                *reinterpret_cast<uchar4*>(VsT + vi) = us;
                *reinterpret_cast<uchar4*>(VaT + vi) = ua;
            } else {
                int8_t* base = ((sel == 0) ? Q2 : K2c) + (size_t)(bh * 1024 + nb) * 128 + d;
                #pragma unroll
                for (int r = 0; r < 4; ++r) {
                    const int v0 = (sel == 0) ? a4[r] + sp[r] : sp[r];
                    const int v1 = (sel == 0) ? sp[r]         : a4[r];
                    base[r * 128]      = (int8_t)v0;
                    base[r * 128 + 64] = (int8_t)v1;
                }
            }
        }
    }
}

// -------------------------------------------------------------------------
// Kernel 2 (fused, int8/int16, 32 KiB LDS, 4 blocks/CU) — unchanged.
// -------------------------------------------------------------------------
__global__ __launch_bounds__(256, 4) void k_attn(
    const int8_t* __restrict__ Q2, const int8_t* __restrict__ K2c,
    const float* __restrict__ avm, const int* __restrict__ aac,
    const int8_t* __restrict__ VsT, const int8_t* __restrict__ VaT,
    bf16* __restrict__ O2)
{
    __shared__ alignas(16) char Sc[32768];
    short* const Ss = (short*)Sc;
    const int w = threadIdx.x >> 6, lane = threadIdx.x & 63;
    const int lo = lane & 15, hi = lane >> 4;
    const int h = blockIdx.y, bb = blockIdx.z;
    const int bh = bb * 8 + h;
    const int n0 = blockIdx.x * 16;

    // ---- Phase 1: scores (i8 MFMA, K=64 x2) -> S int16 ----
    {
        const int8_t* qb = Q2 + ((size_t)(bh * 1024 + n0 + lo)) * 128 + hi * 16;
        const int4v a0 = *reinterpret_cast<const int4v*>(qb);
        const int4v a1 = *reinterpret_cast<const int4v*>(qb + 64);
        const int8_t* kbp = K2c + ((size_t)(bh * 1024 + w * 256 + lo)) * 128 + hi * 16;
        int4v b0 = *reinterpret_cast<const int4v*>(kbp);
        int4v b1 = *reinterpret_cast<const int4v*>(kbp + 64);
        for (int t = 0; t < 16; ++t) {
            const int4v c0f = b0, c1f = b1;
            if (t < 15) {
                kbp += 16 * 128;
                b0 = *reinterpret_cast<const int4v*>(kbp);
                b1 = *reinterpret_cast<const int4v*>(kbp + 64);
            }
            int4v acc = {0, 0, 0, 0};
            acc = MFMAI8(a0, c0f, acc);
            acc = MFMAI8(a1, c1f, acc);
            const int cc = w * 256 + t * 16 + lo;
            short* sb = Ss + ((cc >> 9) << 13) + (cc & 511);
            #pragma unroll
            for (int r = 0; r < 4; ++r)
                sb[(hi * 4 + r) << 9] = (short)acc[r];
        }
    }

    const int row = threadIdx.x >> 4, q = threadIdx.x & 15;
    const size_t gRow = ((size_t)bh * 1024 + (n0 + row)) * 1024;

#define LOADJ(j, VM0, VM1, AC0, AC1) {                                          \
        const int cb_ = (q + 16 * (j)) * 8;                                     \
        VM0 = *reinterpret_cast<const float4*>(avm + gRow + cb_);               \
        VM1 = *reinterpret_cast<const float4*>(avm + gRow + cb_ + 4);           \
        AC0 = *reinterpret_cast<const int4*>(aac + gRow + cb_);                 \
        AC1 = *reinterpret_cast<const int4*>(aac + gRow + cb_ + 4); }

    float4 vmA0, vmA1, vmB0, vmB1, vmC0, vmC1;
    int4   acA0, acA1, acB0, acB1, acC0, acC1;
    LOADJ(0, vmA0, vmA1, acA0, acA1);
    LOADJ(1, vmB0, vmB1, acB0, acB1);

    __syncthreads();   // S writes visible

    // ---- Phase 2a: scores -> registers (this thread's 64 cols) ----
    short8 sc[8];
    #pragma unroll
    for (int j = 0; j < 8; ++j) {
        const int kb = q + 16 * j;
        sc[j] = *reinterpret_cast<const short8*>(Sc + ((kb >> 6) << 14) + (row << 10) + ((kb & 63) << 4));
    }
    __syncthreads();   // all score reads done; S space free for P overlay

    LOADJ(2, vmC0, vmC1, acC0, acC1);

    // ---- Phase 2b: max (exact) / sum ----
    int mxi = sc[0][0];
    #pragma unroll
    for (int j = 0; j < 8; ++j)
        #pragma unroll
        for (int i = 0; i < 8; ++i)
            mxi = max(mxi, (int)sc[j][i]);
    float mx = 0.125f * (float)mxi;
    mx = fmaxf(mx, __shfl_xor(mx, 1));
    mx = fmaxf(mx, __shfl_xor(mx, 2));
    mx = fmaxf(mx, __shfl_xor(mx, 4));
    mx = fmaxf(mx, __shfl_xor(mx, 8));

    float sum = 0.f;
    #pragma unroll
    for (int j = 0; j < 8; ++j)
        #pragma unroll
        for (int i = 0; i < 8; ++i)
            sum += expf(0.125f * (float)sc[j][i] - mx);
    sum += __shfl_xor(sum, 1);
    sum += __shfl_xor(sum, 2);
    sum += __shfl_xor(sum, 4);
    sum += __shfl_xor(sum, 8);

    // ---- Phase 3: attn-IF + int8 P pack (overlay S; row-XOR swizzle) ----
#define PSTEP(j, VM0, VM1, AC0, AC1) {                                          \
        const float vmr_[8] = {VM0.x, VM0.y, VM0.z, VM0.w,                      \
                               VM1.x, VM1.y, VM1.z, VM1.w};                     \
        const int aar_[8] = {AC0.x, AC0.y, AC0.z, AC0.w,                        \
                             AC1.x, AC1.y, AC1.z, AC1.w};                       \
        unsigned p1u[8], p2u[8];                                                \
        _Pragma("unroll")                                                       \
        for (int i = 0; i < 8; ++i) {                                           \
            const float e_ = expf(0.125f * (float)sc[j][i] - mx);               \
            const float p7 = (e_ / sum) * 7.0f;                                 \
            const float v_ = (vmr_[i] + 0.2f) + p7;  /* v_ > 0 always */        \
            const int a0i = aar_[i];                 /* in [0,7] */             \
            const int sp = ((v_ >= 1.0f) && (a0i < 7)) ? 1 : 0;                 \
            p1u[i] = (unsigned)(a0i + sp);                                      \
            p2u[i] = (unsigned)sp;                                              \
        }                                                                       \
        uint2 w1, w2;                                                           \
        w1.x = p1u[0] | (p1u[1] << 8) | (p1u[2] << 16) | (p1u[3] << 24);        \
        w1.y = p1u[4] | (p1u[5] << 8) | (p1u[6] << 16) | (p1u[7] << 24);        \
        w2.x = p2u[0] | (p2u[1] << 8) | (p2u[2] << 16) | (p2u[3] << 24);        \
        w2.y = p2u[4] | (p2u[5] << 8) | (p2u[6] << 16) | (p2u[7] << 24);        \
        const int kb = q + 16 * (j);                                            \
        char* pb = Sc + (row << 10) + (((kb << 3) ^ ((row & 7) << 4)));         \
        *reinterpret_cast<uint2*>(pb)         = w1;                             \
        *reinterpret_cast<uint2*>(pb + 16384) = w2; }

    PSTEP(0, vmA0, vmA1, acA0, acA1);
    LOADJ(3, vmA0, vmA1, acA0, acA1);
    PSTEP(1, vmB0, vmB1, acB0, acB1);
    LOADJ(4, vmB0, vmB1, acB0, acB1);
    PSTEP(2, vmC0, vmC1, acC0, acC1);
    LOADJ(5, vmC0, vmC1, acC0, acC1);
    PSTEP(3, vmA0, vmA1, acA0, acA1);
    LOADJ(6, vmA0, vmA1, acA0, acA1);
    PSTEP(4, vmB0, vmB1, acB0, acB1);
    LOADJ(7, vmB0, vmB1, acB0, acB1);
    PSTEP(5, vmC0, vmC1, acC0, acC1);
    PSTEP(6, vmA0, vmA1, acA0, acA1);
    PSTEP(7, vmB0, vmB1, acB0, acB1);

    __syncthreads();   // P fully written

    // ---- Phase 4: PV (i8 MFMA, exact i32), after-attn IF, write O2 ----
    {
        const int d0 = w * 16;
        const int8_t* vs = VsT + ((size_t)(bh * 64 + d0 + lo)) * 1024 + hi * 16;
        const int8_t* va = VaT + ((size_t)(bh * 64 + d0 + lo)) * 1024 + hi * 16;
        int4v nvs = *reinterpret_cast<const int4v*>(vs);
        int4v nva = *reinterpret_cast<const int4v*>(va);
        int4v acc = {0, 0, 0, 0};
        for (int tt = 0; tt < 16; ++tt) {
            const int4v cvs = nvs, cva = nva;
            if (tt < 15) {
                nvs = *reinterpret_cast<const int4v*>(vs + (tt + 1) * 64);
                nva = *reinterpret_cast<const int4v*>(va + (tt + 1) * 64);
            }
            const int off = (tt * 64 + hi * 16) ^ ((lo & 7) << 4);
            const char* pb = Sc + (lo << 10) + off;
            const int4v a1 = *reinterpret_cast<const int4v*>(pb);
            const int4v a2 = *reinterpret_cast<const int4v*>(pb + 16384);
            acc = MFMAI8(a1, cvs, acc);
            acc = MFMAI8(a2, cva, acc);
        }
        #pragma unroll
        for (int r = 0; r < 4; ++r) {
            const int n = n0 + hi * 4 + r;
            const float o = (float)acc[r];          // exact integer
            const float o2 = (o >= 0.5f ? 1.f : 0.f) - (o < -0.5f ? 1.f : 0.f);
            O2[((size_t)(bb * 1024 + n)) * 512 + h * 64 + d0 + lo] = __float2bfloat16(o2);
        }
    }
#undef LOADJ
#undef PSTEP
}

// -------------------------------------------------------------------------
// Kernel 3: Y = O2 @ Wp^T + b_proj, f32 out (unchanged).
// -------------------------------------------------------------------------
__global__ __launch_bounds__(256) void k_proj(
    const bf16* __restrict__ O2, const bf16* __restrict__ W, const float* __restrict__ bias,
    float* __restrict__ Y)
{
    const int w = threadIdx.x >> 6, lane = threadIdx.x & 63;
    const int lo = lane & 15, hi = lane >> 4;
    const int r0 = blockIdx.y * 16;
    const int c0 = blockIdx.x * 256 + w * 64;

    f32x4 acc[4] = {{0.f,0.f,0.f,0.f},{0.f,0.f,0.f,0.f},{0.f,0.f,0.f,0.f},{0.f,0.f,0.f,0.f}};
    const bf16* op = O2 + (size_t)(r0 + lo) * 512 + hi * 8;
    #pragma unroll 4
    for (int kb = 0; kb < 16; ++kb) {
        short8 a = ldb8(op + kb * 32);
        #pragma unroll
        for (int t = 0; t < 4; ++t) {
            short8 b = ldb8(W + (size_t)(c0 + t * 16 + lo) * 512 + kb * 32 + hi * 8);
            acc[t] = MFMA16(a, b, acc[t]);
        }
    }
    #pragma unroll
    for (int t = 0; t < 4; ++t) {
        const int col = c0 + t * 16 + lo;
        const float bcol = bias[col];
        #pragma unroll
        for (int r = 0; r < 4; ++r) {
            const int rr = r0 + hi * 4 + r;
            Y[(size_t)rr * 512 + col] = acc[t][r] + bcol;
        }
    }
}

// -------------------------------------------------------------------------
extern "C" void kernel_launch(void* const* d_in, const int* in_sizes, int n_in,
                              void* d_out, int out_size, void* d_ws, size_t ws_size,
                              hipStream_t stream)
{
    const float* x     = (const float*)d_in[0];
    const float* wqkv  = (const float*)d_in[1];
    const float* bqkv  = (const float*)d_in[2];
    const float* wproj = (const float*)d_in[3];
    const float* bproj = (const float*)d_in[4];
    const float* qvm   = (const float*)d_in[5];
    const float* kvm   = (const float*)d_in[6];
    const float* vvm   = (const float*)d_in[7];
    const float* avm   = (const float*)d_in[8];
    const int*   qac   = (const int*)d_in[9];
    const int*   kac   = (const int*)d_in[10];
    const int*   vac   = (const int*)d_in[11];
    const int*   aac   = (const int*)d_in[12];

    char* p = (char*)d_ws;
    int8_t*   Q2  = (int8_t*)p;   p += (size_t)32 * 1024 * 128;     // 4 MB  [bh][n][128]
    int8_t*   K2c = (int8_t*)p;   p += (size_t)32 * 1024 * 128;     // 4 MB  [bh][m][128]
    int8_t*   VsT = (int8_t*)p;   p += (size_t)32 * 64 * 1024;      // 2 MB  [bh][d][m]
    int8_t*   VaT = (int8_t*)p;   p += (size_t)32 * 64 * 1024;      // 2 MB
    bf16*     O2  = (bf16*)p;     p += (size_t)4096 * 512 * 2;      // 4 MB  [B*N][C]
    bf16*     Wpb = (bf16*)p;     p += (size_t)512 * 512 * 2;       // 0.5MB w_proj bf16
    _Float16* Xh  = (_Float16*)p; p += (size_t)4096 * 512 * 2;      // 4 MB
    _Float16* Xl  = (_Float16*)p; p += (size_t)4096 * 512 * 2;      // 4 MB
    _Float16* Wh  = (_Float16*)p; p += (size_t)1536 * 512 * 2;      // 1.5 MB
    _Float16* Wl  = (_Float16*)p; p += (size_t)1536 * 512 * 2;      // 1.5 MB

    k_prep<<<dim3(2048), 256, 0, stream>>>(x, wqkv, wproj, Xh, Xl, Wh, Wl, Wpb);
    k_qkv_f16<<<dim3(12, 64), 256, 0, stream>>>(Xh, Xl, Wh, Wl, bqkv, qvm, kvm, vvm,
                                                qac, kac, vac, Q2, K2c, VsT, VaT);
    k_attn<<<dim3(64, 8, 4), 256, 0, stream>>>(Q2, K2c, avm, aac, VsT, VaT, O2);
    k_proj<<<dim3(2, 256), 256, 0, stream>>>(O2, Wpb, bproj, (float*)d_out);
}